// Round 5
// baseline (746.541 us; speedup 1.0000x reference)
//
#include <hip/hip_runtime.h>

#define N_NODES 50000
#define E_EDGES 640000
#define F 128
#define ROWS 16

// -------- Kernel 1: edge scatter (atomic mean-aggregation numerator + counts)
// One wave (64 lanes) per edge; each lane handles 2 features (float2).
__global__ __launch_bounds__(256) void gnn_scatter(
    const float* __restrict__ x,
    const int* __restrict__ ei,      // [2, E]: row 0 = src, row 1 = dst
    float* __restrict__ summed,      // [N, F] accumulates into d_out
    float* __restrict__ counts) {    // [N]
    const int lane = threadIdx.x & 63;
    const int wave = (blockIdx.x * blockDim.x + threadIdx.x) >> 6;
    const int nwaves = (gridDim.x * blockDim.x) >> 6;
    for (int e = wave; e < E_EDGES; e += nwaves) {
        const int src = ei[e];
        const int dst = ei[E_EDGES + e];
        const float2 v =
            *reinterpret_cast<const float2*>(x + (size_t)src * F + lane * 2);
        float* sp = summed + (size_t)dst * F + lane * 2;
        atomicAdd(sp, v.x);
        atomicAdd(sp + 1, v.y);
        if (lane == 0) atomicAdd(counts + dst, 1.0f);
    }
}

// -------- Kernel 2: fused finalize: out = relu(mean @ W_l + x @ W_r + b)
// Block handles ROWS=16 node rows. summed lives in `out`; read rows into LDS
// (pre-sync) then overwrite in place (post-sync) — rows are block-exclusive.
__global__ __launch_bounds__(256) void gnn_finalize(
    const float* __restrict__ x,
    const float* __restrict__ Wl,    // [F, F] row-major (k, c)
    const float* __restrict__ Wr,
    const float* __restrict__ b,
    const float* __restrict__ counts,
    float* __restrict__ out) {       // in: summed, out: result
    __shared__ float mean_s[ROWS][F];
    __shared__ float x_s[ROWS][F];
    const int r0 = blockIdx.x * ROWS;
    const int t = threadIdx.x;

    for (int i = t; i < ROWS * F; i += 256) {
        const int r = i >> 7;
        const int c = i & 127;
        const int row = r0 + r;
        float cnt = 1.0f, sv = 0.0f, xv = 0.0f;
        if (row < N_NODES) {
            cnt = fmaxf(counts[row], 1.0f);
            sv = out[(size_t)row * F + c];
            xv = x[(size_t)row * F + c];
        }
        mean_s[r][c] = sv / cnt;
        x_s[r][c] = xv;
    }
    __syncthreads();

    const int c = t & 127;
    const int rbase = (t >> 7) * (ROWS / 2);  // 0 or 8
    float acc[ROWS / 2];
    const float bias = b[c];
#pragma unroll
    for (int j = 0; j < ROWS / 2; ++j) acc[j] = bias;

    for (int k = 0; k < F; ++k) {
        const float wl = Wl[k * F + c];
        const float wr = Wr[k * F + c];
#pragma unroll
        for (int j = 0; j < ROWS / 2; ++j) {
            acc[j] += mean_s[rbase + j][k] * wl + x_s[rbase + j][k] * wr;
        }
    }

#pragma unroll
    for (int j = 0; j < ROWS / 2; ++j) {
        const int row = r0 + rbase + j;
        if (row < N_NODES) out[(size_t)row * F + c] = fmaxf(acc[j], 0.0f);
    }
}

extern "C" void kernel_launch(void* const* d_in, const int* in_sizes, int n_in,
                              void* d_out, int out_size, void* d_ws,
                              size_t ws_size, hipStream_t stream) {
    const float* x = (const float*)d_in[0];
    const int* ei = (const int*)d_in[1];
    const float* Wl = (const float*)d_in[2];
    const float* Wr = (const float*)d_in[3];
    const float* b = (const float*)d_in[4];
    float* out = (float*)d_out;          // doubles as `summed` accumulator
    float* counts = (float*)d_ws;        // N floats

    hipMemsetAsync(d_out, 0, (size_t)N_NODES * F * sizeof(float), stream);
    hipMemsetAsync(d_ws, 0, (size_t)N_NODES * sizeof(float), stream);

    // scatter: 4096 blocks * 4 waves = 16384 waves, ~39 edges each
    gnn_scatter<<<4096, 256, 0, stream>>>(x, ei, out, counts);

    // finalize: 50000 / 16 = 3125 blocks
    gnn_finalize<<<(N_NODES + ROWS - 1) / ROWS, 256, 0, stream>>>(
        x, Wl, Wr, b, counts, out);
}

// Round 6
// 434.532 us; speedup vs baseline: 1.7180x; 1.7180x over previous
//
#include <hip/hip_runtime.h>

#define N_NODES 50000
#define E_EDGES 640000
#define F 128
#define ROWS 16

// -------- workspace layout (bytes) --------
#define DEG_OFF 0                   // N int32      (200,000 B)
#define OFF_OFF (256 * 1024)        // N+1 int32    (200,004 B)
#define CUR_OFF (512 * 1024)        // N int32      (200,000 B)
#define SRC_OFF (768 * 1024)        // E int32      (2,560,000 B)  total ~3.35 MB

// -------- Kernel 1: in-degree histogram --------
__global__ __launch_bounds__(256) void gnn_hist(const int* __restrict__ ei,
                                                int* __restrict__ deg) {
    const int i = blockIdx.x * blockDim.x + threadIdx.x;
    const int stride = gridDim.x * blockDim.x;
    for (int e = i; e < E_EDGES; e += stride)
        atomicAdd(&deg[ei[E_EDGES + e]], 1);
}

// -------- Kernel 2: single-block exclusive scan (N=50000) --------
__global__ __launch_bounds__(1024) void gnn_scan(const int* __restrict__ deg,
                                                 int* __restrict__ off,
                                                 int* __restrict__ cur) {
    __shared__ int sdata[1024];
    const int t = threadIdx.x;
    const int CHUNK = (N_NODES + 1023) / 1024;  // 49
    const int base = t * CHUNK;
    int total = 0;
    for (int i = 0; i < CHUNK; ++i) {
        const int idx = base + i;
        if (idx < N_NODES) total += deg[idx];
    }
    sdata[t] = total;
    __syncthreads();
    // Hillis-Steele inclusive scan over 1024 partials
    for (int d = 1; d < 1024; d <<= 1) {
        const int v = (t >= d) ? sdata[t - d] : 0;
        __syncthreads();
        sdata[t] += v;
        __syncthreads();
    }
    int running = (t == 0) ? 0 : sdata[t - 1];
    for (int i = 0; i < CHUNK; ++i) {
        const int idx = base + i;
        if (idx < N_NODES) {
            off[idx] = running;
            cur[idx] = running;
            running += deg[idx];
        }
    }
    if (t == 1023) off[N_NODES] = running;  // = E (thread 1023's chunk is past N)
}

// -------- Kernel 3: bucket-fill src ids in dst order --------
__global__ __launch_bounds__(256) void gnn_fill(const int* __restrict__ ei,
                                                int* __restrict__ cur,
                                                int* __restrict__ srcs) {
    const int i = blockIdx.x * blockDim.x + threadIdx.x;
    const int stride = gridDim.x * blockDim.x;
    for (int e = i; e < E_EDGES; e += stride) {
        const int d = ei[E_EDGES + e];
        const int p = atomicAdd(&cur[d], 1);
        srcs[p] = ei[e];
    }
}

// -------- Kernel 4: gather-aggregate, one wave per node, mean into out --------
__global__ __launch_bounds__(256) void gnn_aggregate(
    const float* __restrict__ x, const int* __restrict__ off,
    const int* __restrict__ srcs, float* __restrict__ out) {
    const int node = blockIdx.x * 4 + (threadIdx.x >> 6);
    if (node >= N_NODES) return;
    const int lane = threadIdx.x & 63;
    const int o0 = off[node];
    const int o1 = off[node + 1];
    float2 acc = {0.f, 0.f};
    for (int j = o0; j < o1; ++j) {
        const int s = srcs[j];  // wave-uniform -> broadcast load
        const float2 v =
            *reinterpret_cast<const float2*>(x + (size_t)s * F + lane * 2);
        acc.x += v.x;
        acc.y += v.y;
    }
    const float inv = 1.0f / (float)max(o1 - o0, 1);
    const float2 m = {acc.x * inv, acc.y * inv};
    *reinterpret_cast<float2*>(out + (size_t)node * F + lane * 2) = m;
}

// -------- Kernel 5: fused finalize: out = relu(mean @ W_l + x @ W_r + b) --------
// mean lives in `out` (from gnn_aggregate); stage rows in LDS then overwrite.
__global__ __launch_bounds__(256) void gnn_finalize(
    const float* __restrict__ x, const float* __restrict__ Wl,
    const float* __restrict__ Wr, const float* __restrict__ b,
    float* __restrict__ out) {
    __shared__ float mean_s[ROWS][F];
    __shared__ float x_s[ROWS][F];
    const int r0 = blockIdx.x * ROWS;
    const int t = threadIdx.x;

    for (int i = t; i < ROWS * F; i += 256) {
        const int r = i >> 7;
        const int c = i & 127;
        const int row = r0 + r;
        float sv = 0.0f, xv = 0.0f;
        if (row < N_NODES) {
            sv = out[(size_t)row * F + c];
            xv = x[(size_t)row * F + c];
        }
        mean_s[r][c] = sv;
        x_s[r][c] = xv;
    }
    __syncthreads();

    const int c = t & 127;
    const int rbase = (t >> 7) * (ROWS / 2);  // 0 or 8
    float acc[ROWS / 2];
    const float bias = b[c];
#pragma unroll
    for (int j = 0; j < ROWS / 2; ++j) acc[j] = bias;

    for (int k = 0; k < F; ++k) {
        const float wl = Wl[k * F + c];
        const float wr = Wr[k * F + c];
#pragma unroll
        for (int j = 0; j < ROWS / 2; ++j) {
            acc[j] += mean_s[rbase + j][k] * wl + x_s[rbase + j][k] * wr;
        }
    }

#pragma unroll
    for (int j = 0; j < ROWS / 2; ++j) {
        const int row = r0 + rbase + j;
        if (row < N_NODES) out[(size_t)row * F + c] = fmaxf(acc[j], 0.0f);
    }
}

extern "C" void kernel_launch(void* const* d_in, const int* in_sizes, int n_in,
                              void* d_out, int out_size, void* d_ws,
                              size_t ws_size, hipStream_t stream) {
    const float* x = (const float*)d_in[0];
    const int* ei = (const int*)d_in[1];
    const float* Wl = (const float*)d_in[2];
    const float* Wr = (const float*)d_in[3];
    const float* b = (const float*)d_in[4];
    float* out = (float*)d_out;

    char* ws = (char*)d_ws;
    int* deg = (int*)(ws + DEG_OFF);
    int* off = (int*)(ws + OFF_OFF);
    int* cur = (int*)(ws + CUR_OFF);
    int* srcs = (int*)(ws + SRC_OFF);

    hipMemsetAsync(deg, 0, N_NODES * sizeof(int), stream);

    gnn_hist<<<2048, 256, 0, stream>>>(ei, deg);
    gnn_scan<<<1, 1024, 0, stream>>>(deg, off, cur);
    gnn_fill<<<2048, 256, 0, stream>>>(ei, cur, srcs);
    gnn_aggregate<<<(N_NODES + 3) / 4, 256, 0, stream>>>(x, off, srcs, out);
    gnn_finalize<<<(N_NODES + ROWS - 1) / ROWS, 256, 0, stream>>>(x, Wl, Wr, b,
                                                                  out);
}

// Round 8
// 245.098 us; speedup vs baseline: 3.0459x; 1.7729x over previous
//
#include <hip/hip_runtime.h>

#define N_NODES 50000
#define E_EDGES 640000
#define F 128

typedef __attribute__((ext_vector_type(8))) short short8;
typedef __attribute__((ext_vector_type(4))) float f32x4;

// -------- workspace layout (bytes), total 3,294,720 (< proven 3,346,432) ----
#define DEG_OFF 0            // N int32
#define OFF_OFF 200704       // N+1 int32
#define CUR_OFF 401408       // N int32
#define BSUM_OFF 601600      // 196 int32
#define BPRE_OFF 602624      // 196 int32
#define WF_OFF 603648        // 32768 bf16 (64 KB) W fragments
#define SRC_OFF 734720       // E int32

__device__ __forceinline__ unsigned short f2bf(float f) {
    unsigned int u = __builtin_bit_cast(unsigned int, f);
    u += 0x7FFFu + ((u >> 16) & 1u);  // round-to-nearest-even
    return (unsigned short)(u >> 16);
}

// -------- Kernel 1: in-degree histogram --------
__global__ __launch_bounds__(256) void gnn_hist(const int* __restrict__ ei,
                                                int* __restrict__ deg) {
    const int i = blockIdx.x * blockDim.x + threadIdx.x;
    const int stride = gridDim.x * blockDim.x;
    for (int e = i; e < E_EDGES; e += stride)
        atomicAdd(&deg[ei[E_EDGES + e]], 1);
}

// -------- Kernel 2a: per-block local scan (196 blocks x 256) --------
__global__ __launch_bounds__(256) void gnn_scan_a(const int* __restrict__ deg,
                                                  int* __restrict__ off,
                                                  int* __restrict__ bsum) {
    __shared__ int s[256];
    const int t = threadIdx.x;
    const int i = blockIdx.x * 256 + t;
    const int v = (i < N_NODES) ? deg[i] : 0;
    s[t] = v;
    __syncthreads();
    for (int d = 1; d < 256; d <<= 1) {
        const int u = (t >= d) ? s[t - d] : 0;
        __syncthreads();
        s[t] += u;
        __syncthreads();
    }
    if (i < N_NODES) off[i] = s[t] - v;  // local exclusive prefix
    if (t == 255) bsum[blockIdx.x] = s[255];
}

// -------- Kernel 2b: scan of 196 block sums (1 block) --------
__global__ __launch_bounds__(256) void gnn_scan_b(const int* __restrict__ bsum,
                                                  int* __restrict__ bpre,
                                                  int* __restrict__ off) {
    __shared__ int s[256];
    const int t = threadIdx.x;
    const int v = (t < 196) ? bsum[t] : 0;
    s[t] = v;
    __syncthreads();
    for (int d = 1; d < 256; d <<= 1) {
        const int u = (t >= d) ? s[t - d] : 0;
        __syncthreads();
        s[t] += u;
        __syncthreads();
    }
    if (t < 196) bpre[t] = s[t] - v;  // exclusive block prefix
    if (t == 255) off[N_NODES] = s[255];  // = E
}

// -------- Kernel 2c: add block prefix, init cursors --------
__global__ __launch_bounds__(256) void gnn_scan_c(const int* __restrict__ bpre,
                                                  int* __restrict__ off,
                                                  int* __restrict__ cur) {
    const int i = blockIdx.x * 256 + threadIdx.x;
    if (i < N_NODES) {
        const int o = off[i] + bpre[blockIdx.x];
        off[i] = o;
        cur[i] = o;
    }
}

// -------- Kernel 3: bucket-fill src ids in dst order --------
__global__ __launch_bounds__(256) void gnn_fill(const int* __restrict__ ei,
                                                int* __restrict__ cur,
                                                int* __restrict__ srcs) {
    const int i = blockIdx.x * blockDim.x + threadIdx.x;
    const int stride = gridDim.x * blockDim.x;
    for (int e = i; e < E_EDGES; e += stride) {
        const int d = ei[E_EDGES + e];
        const int p = atomicAdd(&cur[d], 1);
        srcs[p] = ei[e];
    }
}

// -------- Kernel 4: pre-pack W = [Wl;Wr] (256x128) into bf16 B-fragments ----
// Fragment (kstep,ct): lane holds B[k=kstep*32+(lane>>4)*8+j][col=ct*16+(lane&15)]
// stored contiguously at Wf[((kstep*8+ct)*64+lane)*8 + j].
__global__ __launch_bounds__(256) void gnn_wprep(const float* __restrict__ Wl,
                                                 const float* __restrict__ Wr,
                                                 short* __restrict__ Wf) {
    const int tid = blockIdx.x * 256 + threadIdx.x;  // 0..4095
    const int lane = tid & 63;
    const int frag = tid >> 6;  // kstep*8 + ct
    const int kstep = frag >> 3;
    const int ct = frag & 7;
    const int kb = kstep * 32 + (lane >> 4) * 8;
    const int c = ct * 16 + (lane & 15);
    short8 v;
#pragma unroll
    for (int j = 0; j < 8; ++j) {
        const int k = kb + j;
        const float f = (k < F) ? Wl[k * F + c] : Wr[(k - F) * F + c];
        v[j] = (short)f2bf(f);
    }
    *reinterpret_cast<short8*>(Wf + (size_t)tid * 8) = v;
}

// -------- Kernel 5: gather-aggregate, one wave per node, mean into out ------
__global__ __launch_bounds__(256) void gnn_aggregate(
    const float* __restrict__ x, const int* __restrict__ off,
    const int* __restrict__ srcs, float* __restrict__ out) {
    const int node = blockIdx.x * 4 + (threadIdx.x >> 6);
    if (node >= N_NODES) return;
    const int lane = threadIdx.x & 63;
    const int o0 = off[node];
    const int o1 = off[node + 1];
    float2 acc = {0.f, 0.f};
    for (int j = o0; j < o1; ++j) {
        const int s = srcs[j];  // wave-uniform -> broadcast load
        const float2 v =
            *reinterpret_cast<const float2*>(x + (size_t)s * F + lane * 2);
        acc.x += v.x;
        acc.y += v.y;
    }
    const float inv = 1.0f / (float)max(o1 - o0, 1);
    const float2 m = {acc.x * inv, acc.y * inv};
    *reinterpret_cast<float2*>(out + (size_t)node * F + lane * 2) = m;
}

// -------- Kernel 6: MFMA finalize: out = relu([mean|x] @ [Wl;Wr] + b) -------
// Block = 4 waves; wave owns 16 rows x 128 cols. K=256 (mean 0..127, x 128..255).
// A-frag: A[row=lane&15][k=kstep*32+(lane>>4)*8+j], loaded f32 -> cvt bf16.
// D-frag (m89-verified): col=lane&15, row=(lane>>4)*4+reg.
__global__ __launch_bounds__(256) void gnn_finalize_mfma(
    const float* __restrict__ x, const short* __restrict__ Wf,
    const float* __restrict__ bias, float* __restrict__ out) {
    const int t = threadIdx.x;
    const int lane = t & 63;
    const int wv = t >> 6;
    const int r0 = blockIdx.x * 64 + wv * 16;
    const int rl = lane & 15;
    const int kg = lane >> 4;
    const int arow = r0 + rl;
    const int arow_c = (arow < N_NODES) ? arow : (N_NODES - 1);

    f32x4 acc[8];
#pragma unroll
    for (int ct = 0; ct < 8; ++ct) acc[ct] = (f32x4){0.f, 0.f, 0.f, 0.f};

#pragma unroll
    for (int kstep = 0; kstep < 8; ++kstep) {
        const int k0 = kstep * 32 + kg * 8;  // 0..248, no 128-straddle
        const float* asrc = (kstep < 4) ? (out + (size_t)arow_c * F + k0)
                                        : (x + (size_t)arow_c * F + (k0 - F));
        const float4 a0 = *reinterpret_cast<const float4*>(asrc);
        const float4 a1 = *reinterpret_cast<const float4*>(asrc + 4);
        short8 af;
        af[0] = (short)f2bf(a0.x);
        af[1] = (short)f2bf(a0.y);
        af[2] = (short)f2bf(a0.z);
        af[3] = (short)f2bf(a0.w);
        af[4] = (short)f2bf(a1.x);
        af[5] = (short)f2bf(a1.y);
        af[6] = (short)f2bf(a1.z);
        af[7] = (short)f2bf(a1.w);
#pragma unroll
        for (int ct = 0; ct < 8; ++ct) {
            const short8 bf = *reinterpret_cast<const short8*>(
                Wf + (size_t)((kstep * 8 + ct) * 64 + lane) * 8);
            acc[ct] = __builtin_amdgcn_mfma_f32_16x16x32_bf16(af, bf, acc[ct],
                                                              0, 0, 0);
        }
    }

#pragma unroll
    for (int ct = 0; ct < 8; ++ct) {
        const int c = ct * 16 + rl;
        const float bv = bias[c];
#pragma unroll
        for (int r = 0; r < 4; ++r) {
            const int row = r0 + kg * 4 + r;
            if (row < N_NODES)
                out[(size_t)row * F + c] = fmaxf(acc[ct][r] + bv, 0.0f);
        }
    }
}

extern "C" void kernel_launch(void* const* d_in, const int* in_sizes, int n_in,
                              void* d_out, int out_size, void* d_ws,
                              size_t ws_size, hipStream_t stream) {
    const float* x = (const float*)d_in[0];
    const int* ei = (const int*)d_in[1];
    const float* Wl = (const float*)d_in[2];
    const float* Wr = (const float*)d_in[3];
    const float* b = (const float*)d_in[4];
    float* out = (float*)d_out;

    char* ws = (char*)d_ws;
    int* deg = (int*)(ws + DEG_OFF);
    int* off = (int*)(ws + OFF_OFF);
    int* cur = (int*)(ws + CUR_OFF);
    int* bsum = (int*)(ws + BSUM_OFF);
    int* bpre = (int*)(ws + BPRE_OFF);
    short* Wf = (short*)(ws + WF_OFF);
    int* srcs = (int*)(ws + SRC_OFF);

    hipMemsetAsync(deg, 0, N_NODES * sizeof(int), stream);

    gnn_hist<<<2048, 256, 0, stream>>>(ei, deg);
    gnn_scan_a<<<196, 256, 0, stream>>>(deg, off, bsum);
    gnn_scan_b<<<1, 256, 0, stream>>>(bsum, bpre, off);
    gnn_scan_c<<<196, 256, 0, stream>>>(bpre, off, cur);
    gnn_fill<<<2048, 256, 0, stream>>>(ei, cur, srcs);
    gnn_wprep<<<16, 256, 0, stream>>>(Wl, Wr, Wf);
    gnn_aggregate<<<(N_NODES + 3) / 4, 256, 0, stream>>>(x, off, srcs, out);
    gnn_finalize_mfma<<<(N_NODES + 63) / 64, 256, 0, stream>>>(x, Wf, b, out);
}

// Round 9
// 221.042 us; speedup vs baseline: 3.3774x; 1.1088x over previous
//
#include <hip/hip_runtime.h>

#define N_NODES 50000
#define E_EDGES 640000
#define F 128

typedef __attribute__((ext_vector_type(8))) short short8;
typedef __attribute__((ext_vector_type(4))) float f32x4;

// -------- workspace layout (bytes), total 3,294,720 (< proven 3,346,432) ----
#define DEG_OFF 0            // N int32
#define OFF_OFF 200704       // N+1 int32
#define CUR_OFF 401408       // N int32
#define BSUM_OFF 601600      // 196 int32
#define BPRE_OFF 602624      // 196 int32
#define WF_OFF 603648        // 32768 bf16 (64 KB) W fragments
#define SRC_OFF 734720       // E int32

__device__ __forceinline__ unsigned short f2bf(float f) {
    unsigned int u = __builtin_bit_cast(unsigned int, f);
    u += 0x7FFFu + ((u >> 16) & 1u);  // round-to-nearest-even
    return (unsigned short)(u >> 16);
}

// -------- Kernel 1: in-degree histogram --------
__global__ __launch_bounds__(256) void gnn_hist(const int* __restrict__ ei,
                                                int* __restrict__ deg) {
    const int i = blockIdx.x * blockDim.x + threadIdx.x;
    const int stride = gridDim.x * blockDim.x;
    for (int e = i; e < E_EDGES; e += stride)
        atomicAdd(&deg[ei[E_EDGES + e]], 1);
}

// -------- Kernel 2a: per-block local scan (196 blocks x 256) --------
__global__ __launch_bounds__(256) void gnn_scan_a(const int* __restrict__ deg,
                                                  int* __restrict__ off,
                                                  int* __restrict__ bsum) {
    __shared__ int s[256];
    const int t = threadIdx.x;
    const int i = blockIdx.x * 256 + t;
    const int v = (i < N_NODES) ? deg[i] : 0;
    s[t] = v;
    __syncthreads();
    for (int d = 1; d < 256; d <<= 1) {
        const int u = (t >= d) ? s[t - d] : 0;
        __syncthreads();
        s[t] += u;
        __syncthreads();
    }
    if (i < N_NODES) off[i] = s[t] - v;  // local exclusive prefix
    if (t == 255) bsum[blockIdx.x] = s[255];
}

// -------- Kernel 2b: scan of 196 block sums (1 block) --------
__global__ __launch_bounds__(256) void gnn_scan_b(const int* __restrict__ bsum,
                                                  int* __restrict__ bpre,
                                                  int* __restrict__ off) {
    __shared__ int s[256];
    const int t = threadIdx.x;
    const int v = (t < 196) ? bsum[t] : 0;
    s[t] = v;
    __syncthreads();
    for (int d = 1; d < 256; d <<= 1) {
        const int u = (t >= d) ? s[t - d] : 0;
        __syncthreads();
        s[t] += u;
        __syncthreads();
    }
    if (t < 196) bpre[t] = s[t] - v;  // exclusive block prefix
    if (t == 255) off[N_NODES] = s[255];  // = E
}

// -------- Kernel 2c: add block prefix, init cursors --------
__global__ __launch_bounds__(256) void gnn_scan_c(const int* __restrict__ bpre,
                                                  int* __restrict__ off,
                                                  int* __restrict__ cur) {
    const int i = blockIdx.x * 256 + threadIdx.x;
    if (i < N_NODES) {
        const int o = off[i] + bpre[blockIdx.x];
        off[i] = o;
        cur[i] = o;
    }
}

// -------- Kernel 3: bucket-fill src ids in dst order --------
__global__ __launch_bounds__(256) void gnn_fill(const int* __restrict__ ei,
                                                int* __restrict__ cur,
                                                int* __restrict__ srcs) {
    const int i = blockIdx.x * blockDim.x + threadIdx.x;
    const int stride = gridDim.x * blockDim.x;
    for (int e = i; e < E_EDGES; e += stride) {
        const int d = ei[E_EDGES + e];
        const int p = atomicAdd(&cur[d], 1);
        srcs[p] = ei[e];
    }
}

// -------- Kernel 4: pre-pack W = [Wl;Wr] (256x128) into bf16 B-fragments ----
// Fragment (kstep,ct): lane holds B[k=kstep*32+(lane>>4)*8+j][col=ct*16+(lane&15)]
// stored contiguously at Wf[((kstep*8+ct)*64+lane)*8 + j].
__global__ __launch_bounds__(256) void gnn_wprep(const float* __restrict__ Wl,
                                                 const float* __restrict__ Wr,
                                                 short* __restrict__ Wf) {
    const int tid = blockIdx.x * 256 + threadIdx.x;  // 0..4095
    const int lane = tid & 63;
    const int frag = tid >> 6;  // kstep*8 + ct
    const int kstep = frag >> 3;
    const int ct = frag & 7;
    const int kb = kstep * 32 + (lane >> 4) * 8;
    const int c = ct * 16 + (lane & 15);
    short8 v;
#pragma unroll
    for (int j = 0; j < 8; ++j) {
        const int k = kb + j;
        const float f = (k < F) ? Wl[k * F + c] : Wr[(k - F) * F + c];
        v[j] = (short)f2bf(f);
    }
    *reinterpret_cast<short8*>(Wf + (size_t)tid * 8) = v;
}

// -------- Kernel 5: gather-aggregate, one wave per node, mean into out ------
// MLP version: lanes 0-31 = even neighbor, lanes 32-63 = odd neighbor, each
// lane loads float4 (32 lanes x 16B = one 128-col row). Unroll x2 -> 4
// independent global_load_dwordx4 in flight per iteration (was 1x8B).
__global__ __launch_bounds__(256) void gnn_aggregate(
    const float* __restrict__ x, const int* __restrict__ off,
    const int* __restrict__ srcs, float* __restrict__ out) {
    const int node = blockIdx.x * 4 + (threadIdx.x >> 6);
    if (node >= N_NODES) return;
    const int lane = threadIdx.x & 63;
    const int half = lane >> 5;   // which neighbor of the pair
    const int l32 = lane & 31;    // column group (4 floats)
    const int o0 = off[node];
    const int o1 = off[node + 1];
    f32x4 acc0 = {0.f, 0.f, 0.f, 0.f};
    f32x4 acc1 = {0.f, 0.f, 0.f, 0.f};
    int j = o0;
    for (; j + 4 <= o1; j += 4) {  // 4 neighbors per iteration
        const int sA = srcs[j + half];
        const int sB = srcs[j + 2 + half];
        acc0 += *reinterpret_cast<const f32x4*>(x + (size_t)sA * F + l32 * 4);
        acc1 += *reinterpret_cast<const f32x4*>(x + (size_t)sB * F + l32 * 4);
    }
    for (; j < o1; j += 2) {  // tail: 1-2 neighbors, odd one predicated off
        const int jj = j + half;
        const int s = srcs[(jj < o1) ? jj : o0];
        f32x4 v = *reinterpret_cast<const f32x4*>(x + (size_t)s * F + l32 * 4);
        if (jj >= o1) v = (f32x4){0.f, 0.f, 0.f, 0.f};
        acc0 += v;
    }
    acc0 += acc1;
    // combine the two 32-lane halves (lane i <-> lane i^32)
    f32x4 o;
    o[0] = __shfl_xor(acc0[0], 32, 64);
    o[1] = __shfl_xor(acc0[1], 32, 64);
    o[2] = __shfl_xor(acc0[2], 32, 64);
    o[3] = __shfl_xor(acc0[3], 32, 64);
    acc0 += o;
    if (half == 0) {
        const float inv = 1.0f / (float)max(o1 - o0, 1);
        acc0 *= inv;
        *reinterpret_cast<f32x4*>(out + (size_t)node * F + l32 * 4) = acc0;
    }
}

// -------- Kernel 6: MFMA finalize: out = relu([mean|x] @ [Wl;Wr] + b) -------
// Block = 4 waves; wave owns 16 rows x 128 cols. K=256 (mean 0..127, x 128..255).
// A-frag: A[row=lane&15][k=kstep*32+(lane>>4)*8+j], loaded f32 -> cvt bf16.
// D-frag (m89-verified): col=lane&15, row=(lane>>4)*4+reg.
__global__ __launch_bounds__(256) void gnn_finalize_mfma(
    const float* __restrict__ x, const short* __restrict__ Wf,
    const float* __restrict__ bias, float* __restrict__ out) {
    const int t = threadIdx.x;
    const int lane = t & 63;
    const int wv = t >> 6;
    const int r0 = blockIdx.x * 64 + wv * 16;
    const int rl = lane & 15;
    const int kg = lane >> 4;
    const int arow = r0 + rl;
    const int arow_c = (arow < N_NODES) ? arow : (N_NODES - 1);

    f32x4 acc[8];
#pragma unroll
    for (int ct = 0; ct < 8; ++ct) acc[ct] = (f32x4){0.f, 0.f, 0.f, 0.f};

#pragma unroll
    for (int kstep = 0; kstep < 8; ++kstep) {
        const int k0 = kstep * 32 + kg * 8;  // 0..248, no 128-straddle
        const float* asrc = (kstep < 4) ? (out + (size_t)arow_c * F + k0)
                                        : (x + (size_t)arow_c * F + (k0 - F));
        const float4 a0 = *reinterpret_cast<const float4*>(asrc);
        const float4 a1 = *reinterpret_cast<const float4*>(asrc + 4);
        short8 af;
        af[0] = (short)f2bf(a0.x);
        af[1] = (short)f2bf(a0.y);
        af[2] = (short)f2bf(a0.z);
        af[3] = (short)f2bf(a0.w);
        af[4] = (short)f2bf(a1.x);
        af[5] = (short)f2bf(a1.y);
        af[6] = (short)f2bf(a1.z);
        af[7] = (short)f2bf(a1.w);
#pragma unroll
        for (int ct = 0; ct < 8; ++ct) {
            const short8 bf = *reinterpret_cast<const short8*>(
                Wf + (size_t)((kstep * 8 + ct) * 64 + lane) * 8);
            acc[ct] = __builtin_amdgcn_mfma_f32_16x16x32_bf16(af, bf, acc[ct],
                                                              0, 0, 0);
        }
    }

#pragma unroll
    for (int ct = 0; ct < 8; ++ct) {
        const int c = ct * 16 + rl;
        const float bv = bias[c];
#pragma unroll
        for (int r = 0; r < 4; ++r) {
            const int row = r0 + kg * 4 + r;
            if (row < N_NODES)
                out[(size_t)row * F + c] = fmaxf(acc[ct][r] + bv, 0.0f);
        }
    }
}

extern "C" void kernel_launch(void* const* d_in, const int* in_sizes, int n_in,
                              void* d_out, int out_size, void* d_ws,
                              size_t ws_size, hipStream_t stream) {
    const float* x = (const float*)d_in[0];
    const int* ei = (const int*)d_in[1];
    const float* Wl = (const float*)d_in[2];
    const float* Wr = (const float*)d_in[3];
    const float* b = (const float*)d_in[4];
    float* out = (float*)d_out;

    char* ws = (char*)d_ws;
    int* deg = (int*)(ws + DEG_OFF);
    int* off = (int*)(ws + OFF_OFF);
    int* cur = (int*)(ws + CUR_OFF);
    int* bsum = (int*)(ws + BSUM_OFF);
    int* bpre = (int*)(ws + BPRE_OFF);
    short* Wf = (short*)(ws + WF_OFF);
    int* srcs = (int*)(ws + SRC_OFF);

    hipMemsetAsync(deg, 0, N_NODES * sizeof(int), stream);

    gnn_hist<<<2048, 256, 0, stream>>>(ei, deg);
    gnn_scan_a<<<196, 256, 0, stream>>>(deg, off, bsum);
    gnn_scan_b<<<1, 256, 0, stream>>>(bsum, bpre, off);
    gnn_scan_c<<<196, 256, 0, stream>>>(bpre, off, cur);
    gnn_fill<<<2048, 256, 0, stream>>>(ei, cur, srcs);
    gnn_wprep<<<16, 256, 0, stream>>>(Wl, Wr, Wf);
    gnn_aggregate<<<(N_NODES + 3) / 4, 256, 0, stream>>>(x, off, srcs, out);
    gnn_finalize_mfma<<<(N_NODES + 63) / 64, 256, 0, stream>>>(x, Wf, b, out);
}

// Round 10
// 202.130 us; speedup vs baseline: 3.6934x; 1.0936x over previous
//
#include <hip/hip_runtime.h>

#define N_NODES 50000
#define E_EDGES 640000
#define F 128

typedef __attribute__((ext_vector_type(8))) short short8;
typedef __attribute__((ext_vector_type(4))) float f32x4;

// -------- workspace layout (bytes) --------
#define DEG_OFF 0            // N int32
#define OFF_OFF 200704       // N+1 int32
#define CUR_OFF 401408       // N int32
#define BSUM_OFF 601600      // 196 int32
#define BPRE_OFF 602624      // 196 int32
#define WF_OFF 603648        // 32768 bf16 (64 KB) W fragments
#define SRC_OFF 734720       // E int32 -> ends 3,294,720
#define XBF_OFF 3294720      // N*F bf16 (12.8 MB)
#define MBF_OFF 16094720     // N*F bf16 (12.8 MB)
#define WS_NEED_FULL 28894720ULL

__device__ __forceinline__ unsigned short f2bf(float f) {
    unsigned int u = __builtin_bit_cast(unsigned int, f);
    u += 0x7FFFu + ((u >> 16) & 1u);  // round-to-nearest-even
    return (unsigned short)(u >> 16);
}
__device__ __forceinline__ float bfhi2f(unsigned int hi16) {  // hi16 in bits 31:16
    return __builtin_bit_cast(float, hi16 & 0xFFFF0000u);
}

// -------- Kernel 1: in-degree histogram --------
__global__ __launch_bounds__(256) void gnn_hist(const int* __restrict__ ei,
                                                int* __restrict__ deg) {
    const int i = blockIdx.x * blockDim.x + threadIdx.x;
    const int stride = gridDim.x * blockDim.x;
    for (int e = i; e < E_EDGES; e += stride)
        atomicAdd(&deg[ei[E_EDGES + e]], 1);
}

// -------- Kernel 2a: per-block local scan (196 blocks x 256) --------
__global__ __launch_bounds__(256) void gnn_scan_a(const int* __restrict__ deg,
                                                  int* __restrict__ off,
                                                  int* __restrict__ bsum) {
    __shared__ int s[256];
    const int t = threadIdx.x;
    const int i = blockIdx.x * 256 + t;
    const int v = (i < N_NODES) ? deg[i] : 0;
    s[t] = v;
    __syncthreads();
    for (int d = 1; d < 256; d <<= 1) {
        const int u = (t >= d) ? s[t - d] : 0;
        __syncthreads();
        s[t] += u;
        __syncthreads();
    }
    if (i < N_NODES) off[i] = s[t] - v;
    if (t == 255) bsum[blockIdx.x] = s[255];
}

// -------- Kernel 2b: scan of 196 block sums (1 block) --------
__global__ __launch_bounds__(256) void gnn_scan_b(const int* __restrict__ bsum,
                                                  int* __restrict__ bpre,
                                                  int* __restrict__ off) {
    __shared__ int s[256];
    const int t = threadIdx.x;
    const int v = (t < 196) ? bsum[t] : 0;
    s[t] = v;
    __syncthreads();
    for (int d = 1; d < 256; d <<= 1) {
        const int u = (t >= d) ? s[t - d] : 0;
        __syncthreads();
        s[t] += u;
        __syncthreads();
    }
    if (t < 196) bpre[t] = s[t] - v;
    if (t == 255) off[N_NODES] = s[255];
}

// -------- Kernel 2c: add block prefix, init cursors --------
__global__ __launch_bounds__(256) void gnn_scan_c(const int* __restrict__ bpre,
                                                  int* __restrict__ off,
                                                  int* __restrict__ cur) {
    const int i = blockIdx.x * 256 + threadIdx.x;
    if (i < N_NODES) {
        const int o = off[i] + bpre[blockIdx.x];
        off[i] = o;
        cur[i] = o;
    }
}

// -------- Kernel 3: bucket-fill src ids in dst order --------
__global__ __launch_bounds__(256) void gnn_fill(const int* __restrict__ ei,
                                                int* __restrict__ cur,
                                                int* __restrict__ srcs) {
    const int i = blockIdx.x * blockDim.x + threadIdx.x;
    const int stride = gridDim.x * blockDim.x;
    for (int e = i; e < E_EDGES; e += stride) {
        const int d = ei[E_EDGES + e];
        const int p = atomicAdd(&cur[d], 1);
        srcs[p] = ei[e];
    }
}

// -------- Kernel 4: pre-pack W = [Wl;Wr] (256x128) into bf16 B-fragments ----
__global__ __launch_bounds__(256) void gnn_wprep(const float* __restrict__ Wl,
                                                 const float* __restrict__ Wr,
                                                 short* __restrict__ Wf) {
    const int tid = blockIdx.x * 256 + threadIdx.x;  // 0..4095
    const int lane = tid & 63;
    const int frag = tid >> 6;  // kstep*8 + ct
    const int kstep = frag >> 3;
    const int ct = frag & 7;
    const int kb = kstep * 32 + (lane >> 4) * 8;
    const int c = ct * 16 + (lane & 15);
    short8 v;
#pragma unroll
    for (int j = 0; j < 8; ++j) {
        const int k = kb + j;
        const float f = (k < F) ? Wl[k * F + c] : Wr[(k - F) * F + c];
        v[j] = (short)f2bf(f);
    }
    *reinterpret_cast<short8*>(Wf + (size_t)tid * 8) = v;
}

// -------- Kernel 4b: cast x -> bf16 table --------
__global__ __launch_bounds__(256) void gnn_xcast(const float* __restrict__ x,
                                                 unsigned short* __restrict__ xbf) {
    const size_t i = ((size_t)blockIdx.x * 256 + threadIdx.x) * 8;
    if (i >= (size_t)N_NODES * F) return;
    const float4 a0 = *reinterpret_cast<const float4*>(x + i);
    const float4 a1 = *reinterpret_cast<const float4*>(x + i + 4);
    short8 v;
    v[0] = (short)f2bf(a0.x); v[1] = (short)f2bf(a0.y);
    v[2] = (short)f2bf(a0.z); v[3] = (short)f2bf(a0.w);
    v[4] = (short)f2bf(a1.x); v[5] = (short)f2bf(a1.y);
    v[6] = (short)f2bf(a1.z); v[7] = (short)f2bf(a1.w);
    *reinterpret_cast<short8*>((short*)xbf + i) = v;
}

// -------- Kernel 5 (full): bf16 gather-aggregate, mean -> mbf (bf16) --------
// Wave per node. Halves of the wave take alternating neighbors; lane covers
// 4 cols (8 B). 8 neighbors/iter = 4 loads in flight per half.
__global__ __launch_bounds__(256) void gnn_aggregate_bf(
    const unsigned short* __restrict__ xbf, const int* __restrict__ off,
    const int* __restrict__ srcs, unsigned short* __restrict__ mbf) {
    const int node = blockIdx.x * 4 + (threadIdx.x >> 6);
    if (node >= N_NODES) return;
    const int lane = threadIdx.x & 63;
    const int half = lane >> 5;
    const int l32 = lane & 31;
    const int o0 = off[node];
    const int o1 = off[node + 1];
    const unsigned short* xb = xbf + (size_t)l32 * 4;
    f32x4 acc0 = {0.f, 0.f, 0.f, 0.f}, acc1 = {0.f, 0.f, 0.f, 0.f};
    f32x4 acc2 = {0.f, 0.f, 0.f, 0.f}, acc3 = {0.f, 0.f, 0.f, 0.f};
    int j = o0;
    for (; j + 8 <= o1; j += 8) {
        const uint2 a = *reinterpret_cast<const uint2*>(xb + (size_t)srcs[j + half] * F);
        const uint2 b = *reinterpret_cast<const uint2*>(xb + (size_t)srcs[j + 2 + half] * F);
        const uint2 c = *reinterpret_cast<const uint2*>(xb + (size_t)srcs[j + 4 + half] * F);
        const uint2 d = *reinterpret_cast<const uint2*>(xb + (size_t)srcs[j + 6 + half] * F);
        acc0[0] += bfhi2f(a.x << 16); acc0[1] += bfhi2f(a.x);
        acc0[2] += bfhi2f(a.y << 16); acc0[3] += bfhi2f(a.y);
        acc1[0] += bfhi2f(b.x << 16); acc1[1] += bfhi2f(b.x);
        acc1[2] += bfhi2f(b.y << 16); acc1[3] += bfhi2f(b.y);
        acc2[0] += bfhi2f(c.x << 16); acc2[1] += bfhi2f(c.x);
        acc2[2] += bfhi2f(c.y << 16); acc2[3] += bfhi2f(c.y);
        acc3[0] += bfhi2f(d.x << 16); acc3[1] += bfhi2f(d.x);
        acc3[2] += bfhi2f(d.y << 16); acc3[3] += bfhi2f(d.y);
    }
    for (; j + 4 <= o1; j += 4) {
        const uint2 a = *reinterpret_cast<const uint2*>(xb + (size_t)srcs[j + half] * F);
        const uint2 b = *reinterpret_cast<const uint2*>(xb + (size_t)srcs[j + 2 + half] * F);
        acc0[0] += bfhi2f(a.x << 16); acc0[1] += bfhi2f(a.x);
        acc0[2] += bfhi2f(a.y << 16); acc0[3] += bfhi2f(a.y);
        acc1[0] += bfhi2f(b.x << 16); acc1[1] += bfhi2f(b.x);
        acc1[2] += bfhi2f(b.y << 16); acc1[3] += bfhi2f(b.y);
    }
    for (; j < o1; j += 2) {
        const int jj = j + half;
        const uint2 a = *reinterpret_cast<const uint2*>(
            xb + (size_t)srcs[(jj < o1) ? jj : o0] * F);
        if (jj < o1) {
            acc0[0] += bfhi2f(a.x << 16); acc0[1] += bfhi2f(a.x);
            acc0[2] += bfhi2f(a.y << 16); acc0[3] += bfhi2f(a.y);
        }
    }
    acc0 += acc1 + acc2 + acc3;
    f32x4 o;
    o[0] = __shfl_xor(acc0[0], 32, 64);
    o[1] = __shfl_xor(acc0[1], 32, 64);
    o[2] = __shfl_xor(acc0[2], 32, 64);
    o[3] = __shfl_xor(acc0[3], 32, 64);
    acc0 += o;
    if (half == 0) {
        const float inv = 1.0f / (float)max(o1 - o0, 1);
        acc0 *= inv;
        ushort4 m;
        m.x = f2bf(acc0[0]); m.y = f2bf(acc0[1]);
        m.z = f2bf(acc0[2]); m.w = f2bf(acc0[3]);
        *reinterpret_cast<ushort4*>(mbf + (size_t)node * F + l32 * 4) = m;
    }
}

// -------- Kernel 6 (full): MFMA finalize from bf16 tables ------------------
// A-frags load directly as short8 from mbf (kstep<4) / xbf (kstep>=4).
__global__ __launch_bounds__(256) void gnn_finalize_bf(
    const unsigned short* __restrict__ xbf, const unsigned short* __restrict__ mbf,
    const short* __restrict__ Wf, const float* __restrict__ bias,
    float* __restrict__ out) {
    const int t = threadIdx.x;
    const int lane = t & 63;
    const int wv = t >> 6;
    const int r0 = blockIdx.x * 64 + wv * 16;
    const int rl = lane & 15;
    const int kg = lane >> 4;
    const int arow = r0 + rl;
    const int arow_c = (arow < N_NODES) ? arow : (N_NODES - 1);

    f32x4 acc[8];
#pragma unroll
    for (int ct = 0; ct < 8; ++ct) acc[ct] = (f32x4){0.f, 0.f, 0.f, 0.f};

#pragma unroll
    for (int kstep = 0; kstep < 8; ++kstep) {
        const int k0 = kstep * 32 + kg * 8;
        const unsigned short* asrc =
            (kstep < 4) ? (mbf + (size_t)arow_c * F + k0)
                        : (xbf + (size_t)arow_c * F + (k0 - F));
        const short8 af = *reinterpret_cast<const short8*>(asrc);
#pragma unroll
        for (int ct = 0; ct < 8; ++ct) {
            const short8 bf = *reinterpret_cast<const short8*>(
                Wf + (size_t)((kstep * 8 + ct) * 64 + lane) * 8);
            acc[ct] = __builtin_amdgcn_mfma_f32_16x16x32_bf16(af, bf, acc[ct],
                                                              0, 0, 0);
        }
    }

#pragma unroll
    for (int ct = 0; ct < 8; ++ct) {
        const int c = ct * 16 + rl;
        const float bv = bias[c];
#pragma unroll
        for (int r = 0; r < 4; ++r) {
            const int row = r0 + kg * 4 + r;
            if (row < N_NODES)
                out[(size_t)row * F + c] = fmaxf(acc[ct][r] + bv, 0.0f);
        }
    }
}

// ======== fallback (round-9 proven) kernels: f32 gather via out ============
__global__ __launch_bounds__(256) void gnn_aggregate(
    const float* __restrict__ x, const int* __restrict__ off,
    const int* __restrict__ srcs, float* __restrict__ out) {
    const int node = blockIdx.x * 4 + (threadIdx.x >> 6);
    if (node >= N_NODES) return;
    const int lane = threadIdx.x & 63;
    const int half = lane >> 5;
    const int l32 = lane & 31;
    const int o0 = off[node];
    const int o1 = off[node + 1];
    f32x4 acc0 = {0.f, 0.f, 0.f, 0.f};
    f32x4 acc1 = {0.f, 0.f, 0.f, 0.f};
    int j = o0;
    for (; j + 4 <= o1; j += 4) {
        const int sA = srcs[j + half];
        const int sB = srcs[j + 2 + half];
        acc0 += *reinterpret_cast<const f32x4*>(x + (size_t)sA * F + l32 * 4);
        acc1 += *reinterpret_cast<const f32x4*>(x + (size_t)sB * F + l32 * 4);
    }
    for (; j < o1; j += 2) {
        const int jj = j + half;
        const int s = srcs[(jj < o1) ? jj : o0];
        f32x4 v = *reinterpret_cast<const f32x4*>(x + (size_t)s * F + l32 * 4);
        if (jj >= o1) v = (f32x4){0.f, 0.f, 0.f, 0.f};
        acc0 += v;
    }
    acc0 += acc1;
    f32x4 o;
    o[0] = __shfl_xor(acc0[0], 32, 64);
    o[1] = __shfl_xor(acc0[1], 32, 64);
    o[2] = __shfl_xor(acc0[2], 32, 64);
    o[3] = __shfl_xor(acc0[3], 32, 64);
    acc0 += o;
    if (half == 0) {
        const float inv = 1.0f / (float)max(o1 - o0, 1);
        acc0 *= inv;
        *reinterpret_cast<f32x4*>(out + (size_t)node * F + l32 * 4) = acc0;
    }
}

__global__ __launch_bounds__(256) void gnn_finalize_mfma(
    const float* __restrict__ x, const short* __restrict__ Wf,
    const float* __restrict__ bias, float* __restrict__ out) {
    const int t = threadIdx.x;
    const int lane = t & 63;
    const int wv = t >> 6;
    const int r0 = blockIdx.x * 64 + wv * 16;
    const int rl = lane & 15;
    const int kg = lane >> 4;
    const int arow = r0 + rl;
    const int arow_c = (arow < N_NODES) ? arow : (N_NODES - 1);
    f32x4 acc[8];
#pragma unroll
    for (int ct = 0; ct < 8; ++ct) acc[ct] = (f32x4){0.f, 0.f, 0.f, 0.f};
#pragma unroll
    for (int kstep = 0; kstep < 8; ++kstep) {
        const int k0 = kstep * 32 + kg * 8;
        const float* asrc = (kstep < 4) ? (out + (size_t)arow_c * F + k0)
                                        : (x + (size_t)arow_c * F + (k0 - F));
        const float4 a0 = *reinterpret_cast<const float4*>(asrc);
        const float4 a1 = *reinterpret_cast<const float4*>(asrc + 4);
        short8 af;
        af[0] = (short)f2bf(a0.x); af[1] = (short)f2bf(a0.y);
        af[2] = (short)f2bf(a0.z); af[3] = (short)f2bf(a0.w);
        af[4] = (short)f2bf(a1.x); af[5] = (short)f2bf(a1.y);
        af[6] = (short)f2bf(a1.z); af[7] = (short)f2bf(a1.w);
#pragma unroll
        for (int ct = 0; ct < 8; ++ct) {
            const short8 bf = *reinterpret_cast<const short8*>(
                Wf + (size_t)((kstep * 8 + ct) * 64 + lane) * 8);
            acc[ct] = __builtin_amdgcn_mfma_f32_16x16x32_bf16(af, bf, acc[ct],
                                                              0, 0, 0);
        }
    }
#pragma unroll
    for (int ct = 0; ct < 8; ++ct) {
        const int c = ct * 16 + rl;
        const float bv = bias[c];
#pragma unroll
        for (int r = 0; r < 4; ++r) {
            const int row = r0 + kg * 4 + r;
            if (row < N_NODES)
                out[(size_t)row * F + c] = fmaxf(acc[ct][r] + bv, 0.0f);
        }
    }
}

extern "C" void kernel_launch(void* const* d_in, const int* in_sizes, int n_in,
                              void* d_out, int out_size, void* d_ws,
                              size_t ws_size, hipStream_t stream) {
    const float* x = (const float*)d_in[0];
    const int* ei = (const int*)d_in[1];
    const float* Wl = (const float*)d_in[2];
    const float* Wr = (const float*)d_in[3];
    const float* b = (const float*)d_in[4];
    float* out = (float*)d_out;

    char* ws = (char*)d_ws;
    int* deg = (int*)(ws + DEG_OFF);
    int* off = (int*)(ws + OFF_OFF);
    int* cur = (int*)(ws + CUR_OFF);
    int* bsum = (int*)(ws + BSUM_OFF);
    int* bpre = (int*)(ws + BPRE_OFF);
    short* Wf = (short*)(ws + WF_OFF);
    int* srcs = (int*)(ws + SRC_OFF);
    unsigned short* xbf = (unsigned short*)(ws + XBF_OFF);
    unsigned short* mbf = (unsigned short*)(ws + MBF_OFF);

    hipMemsetAsync(deg, 0, N_NODES * sizeof(int), stream);

    gnn_hist<<<2048, 256, 0, stream>>>(ei, deg);
    gnn_scan_a<<<196, 256, 0, stream>>>(deg, off, bsum);
    gnn_scan_b<<<1, 256, 0, stream>>>(bsum, bpre, off);
    gnn_scan_c<<<196, 256, 0, stream>>>(bpre, off, cur);
    gnn_fill<<<2048, 256, 0, stream>>>(ei, cur, srcs);
    gnn_wprep<<<16, 256, 0, stream>>>(Wl, Wr, Wf);

    if (ws_size >= WS_NEED_FULL) {
        gnn_xcast<<<((N_NODES * F / 8) + 255) / 256, 256, 0, stream>>>(x, xbf);
        gnn_aggregate_bf<<<(N_NODES + 3) / 4, 256, 0, stream>>>(xbf, off, srcs,
                                                                mbf);
        gnn_finalize_bf<<<(N_NODES + 63) / 64, 256, 0, stream>>>(xbf, mbf, Wf,
                                                                 b, out);
    } else {
        gnn_aggregate<<<(N_NODES + 3) / 4, 256, 0, stream>>>(x, off, srcs, out);
        gnn_finalize_mfma<<<(N_NODES + 63) / 64, 256, 0, stream>>>(x, Wf, b,
                                                                   out);
    }
}